// Round 1
// 757.840 us; speedup vs baseline: 1.0190x; 1.0190x over previous
//
#include <hip/hip_runtime.h>

#define B_ 512
#define T_ 48
#define D_ 128
#define F_ 16
#define H_ 512
// K = D_*F_ = 2048, gates = 4*H_ = 2048, M = T_*B_ = 24576

typedef float f32x4 __attribute__((ext_vector_type(4)));
typedef short s16x8 __attribute__((ext_vector_type(8)));
typedef unsigned short u16x8 __attribute__((ext_vector_type(8)));
typedef unsigned short u16x4 __attribute__((ext_vector_type(4)));
typedef unsigned long long u64;

__device__ __forceinline__ unsigned short f2bf(float x) {
  unsigned u = __float_as_uint(x);
  u += 0x7fffu + ((u >> 16) & 1u);   // round-to-nearest-even
  return (unsigned short)(u >> 16);
}
__device__ __forceinline__ float bf2f(unsigned short h) {
  return __uint_as_float(((unsigned)h) << 16);
}
__device__ __forceinline__ float sigmoidf_(float x) {
  return 1.f / (1.f + expf(-x));
}

// Relaxed system-scope (sc0 sc1) accesses: bypass L1/L2, coherent at L3.
__device__ __forceinline__ void st_sys_u64(u64* p, u64 v) {
  __hip_atomic_store(p, v, __ATOMIC_RELAXED, __HIP_MEMORY_SCOPE_SYSTEM);
}
__device__ __forceinline__ u64 ld_sys_u64(const u64* p) {
  return __hip_atomic_load((u64*)p, __ATOMIC_RELAXED, __HIP_MEMORY_SCOPE_SYSTEM);
}
__device__ __forceinline__ void st_sys_u32(unsigned* p, unsigned v) {
  __hip_atomic_store(p, v, __ATOMIC_RELAXED, __HIP_MEMORY_SCOPE_SYSTEM);
}
__device__ __forceinline__ unsigned ld_sys_u32(const unsigned* p) {
  return __hip_atomic_load((unsigned*)p, __ATOMIC_RELAXED, __HIP_MEMORY_SCOPE_SYSTEM);
}

#define AS1 __attribute__((address_space(1)))
#define AS3 __attribute__((address_space(3)))
__device__ __forceinline__ void g2lds16(const void* g, void* l) {
  __builtin_amdgcn_global_load_lds((const AS1 void*)g, (AS3 void*)l, 16, 0, 0);
}

// ---------------- K_prep: fp32 -> bf16 weight conversion ----------------
__global__ __launch_bounds__(256) void k_prep(const float* __restrict__ wih,
                                              const float* __restrict__ whh,
                                              unsigned short* __restrict__ wih_b,
                                              unsigned short* __restrict__ whh_b) {
  long i4 = ((long)blockIdx.x * 256 + threadIdx.x) * 4;
  if (i4 < 4194304) {
    float4 v = *(const float4*)(wih + i4);
    u16x4 o = {f2bf(v.x), f2bf(v.y), f2bf(v.z), f2bf(v.w)};
    *(u16x4*)(wih_b + i4) = o;
  } else {
    long j = i4 - 4194304;
    if (j < 1048576) {
      float4 v = *(const float4*)(whh + j);
      u16x4 o = {f2bf(v.x), f2bf(v.y), f2bf(v.z), f2bf(v.w)};
      *(u16x4*)(whh_b + j) = o;
    }
  }
}

// ---------------- K_ex: e_x = x_flat @ w_x + b, then softmax over D -----
__global__ __launch_bounds__(128) void k_ex(const float* __restrict__ in,
                                            const float* __restrict__ attn_w,
                                            const float* __restrict__ attn_b,
                                            float* __restrict__ a_out) {
  __shared__ float wx[768];
  __shared__ float red[128];
  const int b = blockIdx.x, d = threadIdx.x;
  for (int i = d; i < 768; i += 128) wx[i] = attn_w[1024 + i];
  __syncthreads();
  const float* base = in + (long)b * 98304 + (long)d * 16;
  float acc = 0.f;
  for (int t = 0; t < 48; ++t) {
    const float4* p = (const float4*)(base + (long)t * 2048);
    float4 v0 = p[0], v1 = p[1], v2 = p[2], v3 = p[3];
    acc += v0.x * wx[t]       + v0.y * wx[48 + t]  + v0.z * wx[96 + t]  + v0.w * wx[144 + t];
    acc += v1.x * wx[192 + t] + v1.y * wx[240 + t] + v1.z * wx[288 + t] + v1.w * wx[336 + t];
    acc += v2.x * wx[384 + t] + v2.y * wx[432 + t] + v2.z * wx[480 + t] + v2.w * wx[528 + t];
    acc += v3.x * wx[576 + t] + v3.y * wx[624 + t] + v3.z * wx[672 + t] + v3.w * wx[720 + t];
  }
  acc += attn_b[0];
  red[d] = acc;
  __syncthreads();
  for (int s = 64; s > 0; s >>= 1) {
    if (d < s) red[d] = fmaxf(red[d], red[d + s]);
    __syncthreads();
  }
  float mx = red[0];
  __syncthreads();
  float ex = expf(acc - mx);
  red[d] = ex;
  __syncthreads();
  for (int s = 64; s > 0; s >>= 1) {
    if (d < s) red[d] += red[d + s];
    __syncthreads();
  }
  a_out[b * 128 + d] = ex / red[0];
}

// ---------------- K_xhat: x_hat[t*512+b][d*16+f] = a[b,d]*x[b,t,d,f] (bf16)
__global__ __launch_bounds__(256) void k_xhat(const float* __restrict__ in,
                                              const float* __restrict__ a,
                                              unsigned short* __restrict__ xh) {
  const int mrow = blockIdx.x;            // t*512 + b
  const int t = mrow >> 9, b = mrow & 511;
  const int tid = threadIdx.x;
  const int k = tid * 8;
  const int d = k >> 4;
  const int f0 = k & 15;
  const float* src = in + (((long)(b * 48 + t) * 128 + d) * 16 + f0);
  float4 v0 = *(const float4*)src;
  float4 v1 = *(const float4*)(src + 4);
  float s = a[b * 128 + d];
  u16x8 o;
  o[0] = f2bf(v0.x * s); o[1] = f2bf(v0.y * s); o[2] = f2bf(v0.z * s); o[3] = f2bf(v0.w * s);
  o[4] = f2bf(v1.x * s); o[5] = f2bf(v1.y * s); o[6] = f2bf(v1.z * s); o[7] = f2bf(v1.w * s);
  *(u16x8*)(xh + (long)mrow * 2048 + k) = o;
}

// ---------------- K_gemm: 256x256 pipelined bf16 MFMA GEMM ----------------
// gates_x = x_hat(24576x2048) @ w_ih^T(2048 gates x 2048 K), bf16 in/out.
// BM=BN=256, BK=64, 512 thr = 8 waves (2M x 4N); per-wave C = 128x64,
// acc = 8x4 f32x4 (128 VGPR). LDS 128 KiB: A,B double-buffered, each buffer
// split into two 32-wide k-halves (kh0/kh1), 16 KB per half per matrix.
// Swizzle: 16B chunk position = q ^ (row&3), applied via pre-swizzled GLOBAL
// source (global_load_lds lane mapping is linear) and XORed on the read side
// -> 2-way bank aliasing only (free).
// Schedule per K-tile: 4 phases (ks-half x M-half), 16 MFMA each (setprio-
// wrapped). Staging slots (4 loads/thr): ph0 -> kh1(kt+1), ph2 -> kh0(kt+2);
// each half lands ~6 phases before its first ds_read. Counted gates
// s_waitcnt vmcnt(8) at ph1/ph3 ends, immediately before a barrier (per-wave
// count + barrier => cross-wave guarantee). Never vmcnt(0) in steady state.
// Region lifetimes: kh0(kt) last read ph1 (freed at ph1 post-MFMA barrier,
// restaged ph2); kh1(kt) last read ph3 (freed at ph3 barrier, restaged next
// tile's ph0). Gate asm ("memory") also pins compile-time issue order.

#define G_STAGE(ktv, ksv)                                                       \
  do {                                                                          \
    const long ko_ = (long)(ktv) * 64 + (ksv) * 32;                             \
    char* la_ = (char*)SM + ((ktv) & 1) * 32768 + (ksv) * 16384 + ldsw;         \
    g2lds16(Ag + ko_, la_);                                                     \
    g2lds16(Ag + ko_ + 262144, la_ + 8192);                                     \
    g2lds16(Bg + ko_, la_ + 65536);                                             \
    g2lds16(Bg + ko_ + 262144, la_ + 73728);                                    \
  } while (0)

#define G_LDA(bufel, ksv, mh)                                                   \
  do {                                                                          \
    const unsigned short* ab_ = SM + (bufel) + (ksv) * 8192 + aoff0 + (mh) * 2048; \
    af[0] = *(const s16x8*)(ab_);                                               \
    af[1] = *(const s16x8*)(ab_ + 512);                                         \
    af[2] = *(const s16x8*)(ab_ + 1024);                                        \
    af[3] = *(const s16x8*)(ab_ + 1536);                                        \
  } while (0)

#define G_LDB(bufel, ksv)                                                       \
  do {                                                                          \
    const unsigned short* bb_ = SM + (bufel) + (ksv) * 8192 + boff0;            \
    bv[0] = *(const s16x8*)(bb_);                                               \
    bv[1] = *(const s16x8*)(bb_ + 512);                                         \
    bv[2] = *(const s16x8*)(bb_ + 1024);                                        \
    bv[3] = *(const s16x8*)(bb_ + 1536);                                        \
  } while (0)

#define G_BARW()                                                                \
  do {                                                                          \
    __builtin_amdgcn_s_barrier();                                               \
    asm volatile("s_waitcnt lgkmcnt(0)" ::: "memory");                          \
    __builtin_amdgcn_sched_barrier(0);                                          \
  } while (0)

#define G_MMA(mh)                                                               \
  do {                                                                          \
    __builtin_amdgcn_s_setprio(1);                                              \
    _Pragma("unroll") for (int mt_ = 0; mt_ < 4; ++mt_)                         \
        _Pragma("unroll") for (int nt_ = 0; nt_ < 4; ++nt_)                     \
            acc[(mh) * 4 + mt_][nt_] = __builtin_amdgcn_mfma_f32_16x16x32_bf16( \
                af[mt_], bv[nt_], acc[(mh) * 4 + mt_][nt_], 0, 0, 0);           \
    __builtin_amdgcn_s_setprio(0);                                              \
  } while (0)

#define G_GATE(n) asm volatile("s_waitcnt vmcnt(" #n ")" ::: "memory")

__global__ __launch_bounds__(512, 2) void k_gemm(const unsigned short* __restrict__ A,
                                                 const unsigned short* __restrict__ Bw,
                                                 unsigned short* __restrict__ C) {
  __shared__ __align__(16) unsigned short SM[65536];  // A bytes [0,64K), B [64K,128K)
  const int tid = threadIdx.x;
  const int w = tid >> 6, lane = tid & 63;
  const int q = lane >> 4, l16 = lane & 15;
  const int wm = w >> 2, wn = w & 3;
  const int id = blockIdx.x;
  const int xcd = id & 7, j = id >> 3;                 // 768 = 8 XCD * 96, bijective
  const long m0 = ((long)xcd * 12 + (j >> 3)) * 256;   // 96 m-tiles
  const long n0 = (long)(j & 7) * 256;                 // 8 n-tiles, fastest

  // staging invariants: thread covers (row = w*16 + lane>>2 [+128*round],
  // chunk pos = lane&3); source chunk pre-swizzled so linear LDS lands swizzled
  const int srow = w * 16 + (lane >> 2);
  const int csrc = (lane & 3) ^ ((lane >> 2) & 3);
  const unsigned short* Ag = A + (m0 + srow) * 2048 + csrc * 8;
  const unsigned short* Bg = Bw + (n0 + srow) * 2048 + csrc * 8;
  const int ldsw = w * 1024;                           // wave-uniform LDS base

  // fragment read offsets (element units); position = q ^ (row&3) = q ^ (l16&3)
  const int psw = (q ^ (l16 & 3)) * 8;
  const int aoff0 = (wm * 128 + l16) * 32 + psw;       // + mh*2048 + mt*512
  const int boff0 = 32768 + (wn * 64 + l16) * 32 + psw;// + nt*512

  f32x4 acc[8][4];
  const f32x4 zz = {0.f, 0.f, 0.f, 0.f};
#pragma unroll
  for (int i = 0; i < 8; ++i)
#pragma unroll
    for (int j2 = 0; j2 < 4; ++j2) acc[i][j2] = zz;
  s16x8 af[4], bv[4];

  // prologue: kh0(0), kh1(0), kh0(1); gate leaves 2 newest slots in flight
  G_STAGE(0, 0);
  G_STAGE(0, 1);
  G_STAGE(1, 0);
  G_GATE(8);
  __builtin_amdgcn_s_barrier();

#pragma unroll 2
  for (int kt = 0; kt < 30; ++kt) {
    const int bufel = (kt & 1) * 16384;
    // ph0: ks0, mh0
    G_LDB(bufel, 0); G_LDA(bufel, 0, 0);
    G_STAGE(kt + 1, 1);
    G_BARW(); G_MMA(0);
    __builtin_amdgcn_s_barrier();
    // ph1: ks0, mh1
    G_LDA(bufel, 0, 1);
    G_BARW(); G_MMA(1);
    G_GATE(8);                      // kh1(kt) resident for ph2
    __builtin_amdgcn_s_barrier();
    // ph2: ks1, mh0
    G_LDB(bufel, 1); G_LDA(bufel, 1, 0);
    G_STAGE(kt + 2, 0);
    G_BARW(); G_MMA(0);
    __builtin_amdgcn_s_barrier();
    // ph3: ks1, mh1
    G_LDA(bufel, 1, 1);
    G_BARW(); G_MMA(1);
    G_GATE(8);                      // kh0(kt+1) resident for next ph0
    __builtin_amdgcn_s_barrier();
  }
  {  // kt = 30 (buf 0): last kh1 stage, no kh0 stage
    G_LDB(0, 0); G_LDA(0, 0, 0);
    G_STAGE(31, 1);
    G_BARW(); G_MMA(0);
    __builtin_amdgcn_s_barrier();
    G_LDA(0, 0, 1);
    G_BARW(); G_MMA(1);
    G_GATE(8);
    __builtin_amdgcn_s_barrier();
    G_LDB(0, 1); G_LDA(0, 1, 0);
    G_BARW(); G_MMA(0);
    __builtin_amdgcn_s_barrier();
    G_LDA(0, 1, 1);
    G_BARW(); G_MMA(1);
    G_GATE(4);                      // only kh1(31) may remain in flight
    __builtin_amdgcn_s_barrier();
  }
  {  // kt = 31 (buf 1): drain
    G_LDB(16384, 0); G_LDA(16384, 0, 0);
    G_BARW(); G_MMA(0);
    __builtin_amdgcn_s_barrier();
    G_LDA(16384, 0, 1);
    G_BARW(); G_MMA(1);
    G_GATE(0);
    __builtin_amdgcn_s_barrier();
    G_LDB(16384, 1); G_LDA(16384, 1, 0);
    G_BARW(); G_MMA(0);
    __builtin_amdgcn_s_barrier();
    G_LDA(16384, 1, 1);
    G_BARW(); G_MMA(1);
  }

  // epilogue: C[m][n], row = m0 + wm*128 + mh*64 + mt*16 + q*4 + r, col += l16
#pragma unroll
  for (int mh = 0; mh < 2; ++mh)
#pragma unroll
    for (int mt = 0; mt < 4; ++mt)
#pragma unroll
      for (int nt = 0; nt < 4; ++nt)
#pragma unroll
        for (int r = 0; r < 4; ++r) {
          long m = m0 + wm * 128 + mh * 64 + mt * 16 + q * 4 + r;
          long n = n0 + wn * 64 + nt * 16 + l16;
          C[m * 2048 + n] = f2bf(acc[mh * 4 + mt][nt][r]);
        }
}

// ---------------- K_rec: persistent LSTM scan -----------------------------
__global__ __launch_bounds__(256, 1) void k_rec(const unsigned short* __restrict__ gx,
                                                const unsigned short* __restrict__ whh_b,
                                                const float* __restrict__ b_ih,
                                                const float* __restrict__ b_hh,
                                                unsigned short* __restrict__ h_buf,
                                                float* __restrict__ out,
                                                unsigned int* __restrict__ bar) {
  __shared__ unsigned short hs[32 * 528];   // h(t-1) stage, rows padded to 528
  __shared__ float gsm[4 * 32 * 36];        // [quad][colN 32][rowM pad36]
  const int tid = threadIdx.x;
  const int wave = tid >> 6, lane = tid & 63;   // wave == gate quadrant
  const int q = lane >> 4, l16 = lane & 15;
  const int bt = blockIdx.x & 15, g = blockIdx.x >> 4;
  const int b0 = bt * 32;
  const int pm = tid >> 3, pr = (tid & 7) * 4;  // pointwise: row pm, cols pr..pr+3
  const int srow = tid >> 3, st7 = tid & 7;     // stage: row srow, ull lane st7
  unsigned int* slots = &bar[bt * 16];

  // w_hh fragments -> registers (once), pinned against rematerialization
  s16x8 wreg[32];
#pragma unroll
  for (int nt = 0; nt < 2; ++nt) {
    const unsigned short* wp = whh_b + (long)(wave * 512 + g * 32 + nt * 16 + l16) * 512 + q * 8;
#pragma unroll
    for (int kk = 0; kk < 16; ++kk)
      wreg[nt * 16 + kk] = *(const s16x8*)(wp + kk * 32);
  }
#pragma unroll
  for (int i = 0; i < 32; ++i) asm volatile("" : "+v"(wreg[i]));

  float bias_[16];
#pragma unroll
  for (int qq = 0; qq < 4; ++qq)
#pragma unroll
    for (int rr = 0; rr < 4; ++rr) {
      int j = qq * 512 + g * 32 + pr + rr;
      bias_[qq * 4 + rr] = b_ih[j] + b_hh[j];
    }
  float creg[4] = {0.f, 0.f, 0.f, 0.f};
  const f32x4 zz = {0.f, 0.f, 0.f, 0.f};

  for (int t = 0; t < 48; ++t) {
    // prefetch gx (plain cached loads; read-only, L2 stays warm now)
    u16x4 gxr[4];
    const unsigned short* gp = gx + ((long)t * 512 + b0 + pm) * 2048 + g * 32 + pr;
#pragma unroll
    for (int qq = 0; qq < 4; ++qq) gxr[qq] = *(const u16x4*)(gp + qq * 512);

    f32x4 acc[2][2] = {{zz, zz}, {zz, zz}};
    if (t > 0) {
      // wait for the 16 producer slots of this bt group (relaxed sys polls)
      if (wave == 0 && lane < 16) {
        while (ld_sys_u32(&slots[lane]) < (unsigned)t)
          __builtin_amdgcn_s_sleep(1);
      }
      __syncthreads();
      // stage h(t-1)[b0:b0+32, 0:512] -> LDS (sys loads bypass stale L1/L2)
      const u64* hp = (const u64*)(h_buf + ((t - 1) & 1) * (512 * 512) + (long)b0 * 512);
      u64 tmp[16];
#pragma unroll
      for (int j = 0; j < 16; ++j)
        tmp[j] = ld_sys_u64(hp + (long)srow * 128 + st7 + 8 * j);
#pragma unroll
      for (int j = 0; j < 16; ++j)
        *(u64*)&hs[srow * 528 + (st7 + 8 * j) * 4] = tmp[j];
      __syncthreads();
#pragma unroll
      for (int kk = 0; kk < 16; ++kk) {
        s16x8 af0 = *(const s16x8*)&hs[l16 * 528 + kk * 32 + q * 8];
        s16x8 af1 = *(const s16x8*)&hs[(16 + l16) * 528 + kk * 32 + q * 8];
        acc[0][0] = __builtin_amdgcn_mfma_f32_16x16x32_bf16(af0, wreg[kk],      acc[0][0], 0, 0, 0);
        acc[0][1] = __builtin_amdgcn_mfma_f32_16x16x32_bf16(af0, wreg[16 + kk], acc[0][1], 0, 0, 0);
        acc[1][0] = __builtin_amdgcn_mfma_f32_16x16x32_bf16(af1, wreg[kk],      acc[1][0], 0, 0, 0);
        acc[1][1] = __builtin_amdgcn_mfma_f32_16x16x32_bf16(af1, wreg[16 + kk], acc[1][1], 0, 0, 0);
      }
    }
    // acc -> gsm[wave][colN][rowM]; rows mt*16+q*4..+3 contiguous => b128 store
#pragma unroll
    for (int mt = 0; mt < 2; ++mt)
#pragma unroll
      for (int nt = 0; nt < 2; ++nt)
        *(f32x4*)&gsm[(wave * 32 + nt * 16 + l16) * 36 + mt * 16 + q * 4] = acc[mt][nt];
    __syncthreads();
    // pointwise LSTM cell: thread owns (row b0+pm, cols g*32+pr..+3)
    float hval[4];
#pragma unroll
    for (int rr = 0; rr < 4; ++rr) {
      float gv[4];
#pragma unroll
      for (int qq = 0; qq < 4; ++qq)
        gv[qq] = gsm[(qq * 32 + pr + rr) * 36 + pm] + bf2f(gxr[qq][rr]) + bias_[qq * 4 + rr];
      float is = sigmoidf_(gv[0]);
      float fs = sigmoidf_(gv[1]);
      float gt = tanhf(gv[2]);
      float os = sigmoidf_(gv[3]);
      creg[rr] = fs * creg[rr] + is * gt;
      hval[rr] = os * tanhf(creg[rr]);
    }
    // publish h slice via system-scope stores (land in coherent L3)
    u16x4 hb = {f2bf(hval[0]), f2bf(hval[1]), f2bf(hval[2]), f2bf(hval[3])};
    u64 hb8;
    __builtin_memcpy(&hb8, &hb, 8);
    st_sys_u64((u64*)&h_buf[(t & 1) * (512 * 512) + (b0 + pm) * 512 + g * 32 + pr], hb8);
    f32x4 ov = {hval[0], hval[1], hval[2], hval[3]};
    __builtin_nontemporal_store(ov, (f32x4*)&out[(long)(b0 + pm) * (T_ * H_) + (long)t * H_ + g * 32 + pr]);
    __syncthreads();   // drains vmcnt(0): h stores at L3 before flag
    if (t < 47 && tid == 0)
      st_sys_u32(&slots[g], (unsigned)(t + 1));
  }
}

extern "C" void kernel_launch(void* const* d_in, const int* in_sizes, int n_in,
                              void* d_out, int out_size, void* d_ws, size_t ws_size,
                              hipStream_t stream) {
  const float* input  = (const float*)d_in[0];
  const float* attn_w = (const float*)d_in[1];
  const float* attn_b = (const float*)d_in[2];
  const float* w_ih   = (const float*)d_in[3];
  const float* w_hh   = (const float*)d_in[4];
  const float* b_ih   = (const float*)d_in[5];
  const float* b_hh   = (const float*)d_in[6];
  float* out = (float*)d_out;

  char* ws = (char*)d_ws;
  unsigned int* bar     = (unsigned int*)ws;                   // [0, 1024)
  float* a_ws           = (float*)(ws + 1024);                 // 512*128*4    = 262144
  unsigned short* h_buf = (unsigned short*)(ws + 263168);      // 2*512*512*2  = 1048576
  unsigned short* whh_b = (unsigned short*)(ws + 1311744);     // 2048*512*2   = 2097152
  unsigned short* wih_b = (unsigned short*)(ws + 3408896);     // 2048*2048*2  = 8388608
  unsigned short* x_hat = (unsigned short*)(ws + 11797504);    // 24576*2048*2 = 100663296
  unsigned short* gxws  = (unsigned short*)(ws + 112460800);   // 24576*2048*2 = 100663296

  (void)hipMemsetAsync(d_ws, 0, 1024, stream);
  hipLaunchKernelGGL(k_prep, dim3(5120), dim3(256), 0, stream, w_ih, w_hh, wih_b, whh_b);
  hipLaunchKernelGGL(k_ex, dim3(512), dim3(128), 0, stream, input, attn_w, attn_b, a_ws);
  hipLaunchKernelGGL(k_xhat, dim3(24576), dim3(256), 0, stream, input, a_ws, x_hat);
  hipLaunchKernelGGL(k_gemm, dim3(768), dim3(512), 0, stream, x_hat, wih_b, gxws);
  hipLaunchKernelGGL(k_rec, dim3(256), dim3(256), 0, stream, gxws, whh_b, b_ih, b_hh, h_buf, out, bar);
}

// Round 2
// 722.615 us; speedup vs baseline: 1.0687x; 1.0487x over previous
//
#include <hip/hip_runtime.h>

#define B_ 512
#define T_ 48
#define D_ 128
#define F_ 16
#define H_ 512
// K = D_*F_ = 2048, gates = 4*H_ = 2048, M = T_*B_ = 24576

typedef float f32x4 __attribute__((ext_vector_type(4)));
typedef short s16x8 __attribute__((ext_vector_type(8)));
typedef unsigned short u16x8 __attribute__((ext_vector_type(8)));
typedef unsigned short u16x4 __attribute__((ext_vector_type(4)));
typedef unsigned long long u64;

__device__ __forceinline__ unsigned short f2bf(float x) {
  unsigned u = __float_as_uint(x);
  u += 0x7fffu + ((u >> 16) & 1u);   // round-to-nearest-even
  return (unsigned short)(u >> 16);
}
__device__ __forceinline__ float bf2f(unsigned short h) {
  return __uint_as_float(((unsigned)h) << 16);
}
__device__ __forceinline__ float sigmoidf_(float x) {
  return 1.f / (1.f + expf(-x));
}

// Relaxed system-scope (sc0 sc1) accesses: bypass L1/L2, coherent at L3.
__device__ __forceinline__ void st_sys_u64(u64* p, u64 v) {
  __hip_atomic_store(p, v, __ATOMIC_RELAXED, __HIP_MEMORY_SCOPE_SYSTEM);
}
__device__ __forceinline__ u64 ld_sys_u64(const u64* p) {
  return __hip_atomic_load((u64*)p, __ATOMIC_RELAXED, __HIP_MEMORY_SCOPE_SYSTEM);
}
__device__ __forceinline__ void st_sys_u32(unsigned* p, unsigned v) {
  __hip_atomic_store(p, v, __ATOMIC_RELAXED, __HIP_MEMORY_SCOPE_SYSTEM);
}
__device__ __forceinline__ unsigned ld_sys_u32(const unsigned* p) {
  return __hip_atomic_load((unsigned*)p, __ATOMIC_RELAXED, __HIP_MEMORY_SCOPE_SYSTEM);
}

#define AS1 __attribute__((address_space(1)))
#define AS3 __attribute__((address_space(3)))
__device__ __forceinline__ void g2lds16(const void* g, void* l) {
  __builtin_amdgcn_global_load_lds((const AS1 void*)g, (AS3 void*)l, 16, 0, 0);
}

// ---------------- K_prep: fp32 -> bf16 weight conversion ----------------
__global__ __launch_bounds__(256) void k_prep(const float* __restrict__ wih,
                                              const float* __restrict__ whh,
                                              unsigned short* __restrict__ wih_b,
                                              unsigned short* __restrict__ whh_b) {
  long i4 = ((long)blockIdx.x * 256 + threadIdx.x) * 4;
  if (i4 < 4194304) {
    float4 v = *(const float4*)(wih + i4);
    u16x4 o = {f2bf(v.x), f2bf(v.y), f2bf(v.z), f2bf(v.w)};
    *(u16x4*)(wih_b + i4) = o;
  } else {
    long j = i4 - 4194304;
    if (j < 1048576) {
      float4 v = *(const float4*)(whh + j);
      u16x4 o = {f2bf(v.x), f2bf(v.y), f2bf(v.z), f2bf(v.w)};
      *(u16x4*)(whh_b + j) = o;
    }
  }
}

// ---------------- K_ex: e_x = x_flat @ w_x + b, then softmax over D -----
__global__ __launch_bounds__(128) void k_ex(const float* __restrict__ in,
                                            const float* __restrict__ attn_w,
                                            const float* __restrict__ attn_b,
                                            float* __restrict__ a_out) {
  __shared__ float wx[768];
  __shared__ float red[128];
  const int b = blockIdx.x, d = threadIdx.x;
  for (int i = d; i < 768; i += 128) wx[i] = attn_w[1024 + i];
  __syncthreads();
  const float* base = in + (long)b * 98304 + (long)d * 16;
  float acc = 0.f;
  for (int t = 0; t < 48; ++t) {
    const float4* p = (const float4*)(base + (long)t * 2048);
    float4 v0 = p[0], v1 = p[1], v2 = p[2], v3 = p[3];
    acc += v0.x * wx[t]       + v0.y * wx[48 + t]  + v0.z * wx[96 + t]  + v0.w * wx[144 + t];
    acc += v1.x * wx[192 + t] + v1.y * wx[240 + t] + v1.z * wx[288 + t] + v1.w * wx[336 + t];
    acc += v2.x * wx[384 + t] + v2.y * wx[432 + t] + v2.z * wx[480 + t] + v2.w * wx[528 + t];
    acc += v3.x * wx[576 + t] + v3.y * wx[624 + t] + v3.z * wx[672 + t] + v3.w * wx[720 + t];
  }
  acc += attn_b[0];
  red[d] = acc;
  __syncthreads();
  for (int s = 64; s > 0; s >>= 1) {
    if (d < s) red[d] = fmaxf(red[d], red[d + s]);
    __syncthreads();
  }
  float mx = red[0];
  __syncthreads();
  float ex = expf(acc - mx);
  red[d] = ex;
  __syncthreads();
  for (int s = 64; s > 0; s >>= 1) {
    if (d < s) red[d] += red[d + s];
    __syncthreads();
  }
  a_out[b * 128 + d] = ex / red[0];
}

// ---------------- K_xhat: x_hat[t*512+b][d*16+f] = a[b,d]*x[b,t,d,f] (bf16)
__global__ __launch_bounds__(256) void k_xhat(const float* __restrict__ in,
                                              const float* __restrict__ a,
                                              unsigned short* __restrict__ xh) {
  const int mrow = blockIdx.x;            // t*512 + b
  const int t = mrow >> 9, b = mrow & 511;
  const int tid = threadIdx.x;
  const int k = tid * 8;
  const int d = k >> 4;
  const int f0 = k & 15;
  const float* src = in + (((long)(b * 48 + t) * 128 + d) * 16 + f0);
  float4 v0 = *(const float4*)src;
  float4 v1 = *(const float4*)(src + 4);
  float s = a[b * 128 + d];
  u16x8 o;
  o[0] = f2bf(v0.x * s); o[1] = f2bf(v0.y * s); o[2] = f2bf(v0.z * s); o[3] = f2bf(v0.w * s);
  o[4] = f2bf(v1.x * s); o[5] = f2bf(v1.y * s); o[6] = f2bf(v1.z * s); o[7] = f2bf(v1.w * s);
  *(u16x8*)(xh + (long)mrow * 2048 + k) = o;
}

// ---------------- K_gemm: 256x256 pipelined bf16 MFMA GEMM ----------------
// gates_x = x_hat(24576x2048) @ w_ih^T(2048 gates x 2048 K), bf16 in/out.
// BM=BN=256, BK=64, 512 thr = 8 waves (2M x 4N); per-wave C = 128x64,
// acc = 8x4 f32x4. LDS 128 KiB (1 block/CU): A [0,64K), B [64K,128K), each
// double-buffered; within a buffer, row r (0..255) is the FULL BK=64 (128 B,
// 8 chunks of 16 B) -> row stride == 0 mod 32 banks.
// Swizzle (m201-style 3-bit): chunk at LDS position p holds logical chunk
// c = p ^ (r&7). Applied at the GLOBAL source (global_load_lds writes
// linearly, lane*16) and XORed on the read side. Read conflict check: 8
// consecutive lanes (fixed q, l16 0..7) read positions (ks*4+q)^l16 -> all 8
// distinct 16B slots -> conflict-free ds_read_b128.
// Staging: slot s = rows [s*128, s*128+128) of A and B for one K-tile
// (4 loads/thread). Tile kt stages BOTH slots of kt+1 at ph0/ph1 -> issued
// 3-4 phases (~1500+ cyc) before first read, > HBM latency, so the single
// vmcnt(0) gate at ph3-end is a non-stall in steady state.
// Phases per tile: (ks, mh) x (0,1); 16 setprio-wrapped MFMA each; B frags
// reused across the two mh phases of each ks.

#define G_STAGE(ktv, s)                                                         \
  do {                                                                          \
    const long ko_ = (long)(ktv) * 64 + (long)(s) * 262144;                     \
    char* la_ = (char*)SM + ((ktv) & 1) * 32768 + (s) * 16384 + ldsw;           \
    g2lds16(Ag + ko_, la_);                                                     \
    g2lds16(Ag + ko_ + 131072, la_ + 8192);                                     \
    g2lds16(Bg + ko_, la_ + 65536);                                             \
    g2lds16(Bg + ko_ + 131072, la_ + 73728);                                    \
  } while (0)

#define G_LDA(bufel, ksv, mh)                                                   \
  do {                                                                          \
    const unsigned short* ab_ =                                                 \
        SM + (bufel) + aBase + (mh) * 4096 + (psw ^ ((ksv) * 32));              \
    af[0] = *(const s16x8*)(ab_);                                               \
    af[1] = *(const s16x8*)(ab_ + 1024);                                        \
    af[2] = *(const s16x8*)(ab_ + 2048);                                        \
    af[3] = *(const s16x8*)(ab_ + 3072);                                        \
  } while (0)

#define G_LDB(bufel, ksv)                                                       \
  do {                                                                          \
    const unsigned short* bb_ = SM + (bufel) + bBase + (psw ^ ((ksv) * 32));    \
    bv[0] = *(const s16x8*)(bb_);                                               \
    bv[1] = *(const s16x8*)(bb_ + 1024);                                        \
    bv[2] = *(const s16x8*)(bb_ + 2048);                                        \
    bv[3] = *(const s16x8*)(bb_ + 3072);                                        \
  } while (0)

#define G_BARW()                                                                \
  do {                                                                          \
    __builtin_amdgcn_s_barrier();                                               \
    asm volatile("s_waitcnt lgkmcnt(0)" ::: "memory");                          \
    __builtin_amdgcn_sched_barrier(0);                                          \
  } while (0)

#define G_MMA(mh)                                                               \
  do {                                                                          \
    __builtin_amdgcn_s_setprio(1);                                              \
    _Pragma("unroll") for (int mt_ = 0; mt_ < 4; ++mt_)                         \
        _Pragma("unroll") for (int nt_ = 0; nt_ < 4; ++nt_)                     \
            acc[(mh) * 4 + mt_][nt_] = __builtin_amdgcn_mfma_f32_16x16x32_bf16( \
                af[mt_], bv[nt_], acc[(mh) * 4 + mt_][nt_], 0, 0, 0);           \
    __builtin_amdgcn_s_setprio(0);                                              \
  } while (0)

#define G_GATE(n) asm volatile("s_waitcnt vmcnt(" #n ")" ::: "memory")

__global__ __launch_bounds__(512, 2) void k_gemm(const unsigned short* __restrict__ A,
                                                 const unsigned short* __restrict__ Bw,
                                                 unsigned short* __restrict__ C) {
  __shared__ __align__(16) unsigned short SM[65536];  // A bytes [0,64K), B [64K,128K)
  const int tid = threadIdx.x;
  const int w = tid >> 6, lane = tid & 63;
  const int q = lane >> 4, l16 = lane & 15;
  const int wm = w >> 2, wn = w & 3;
  const int id = blockIdx.x;
  const int xcd = id & 7, j = id >> 3;                 // 768 = 8 XCD * 96, bijective
  const long m0 = ((long)xcd * 12 + (j >> 3)) * 256;   // 96 m-tiles
  const long n0 = (long)(j & 7) * 256;                 // 8 n-tiles, fastest

  // staging: thread covers (row = s*128 + i*64 + w*8 + (lane>>3), pos = lane&7);
  // source chunk pre-swizzled (csrc = pos ^ (row&7)) so linear LDS lands swizzled
  const int srow = w * 8 + (lane >> 3);
  const int csrc = (lane & 7) ^ (lane >> 3);
  const unsigned short* Ag = A + (m0 + srow) * 2048 + csrc * 8;
  const unsigned short* Bg = Bw + (n0 + srow) * 2048 + csrc * 8;
  const int ldsw = w * 1024;                           // wave-uniform LDS base

  // fragment read offsets (elements); position = (ks*4+q) ^ (row&7), row&7 = l16&7
  const int psw = (q ^ (l16 & 7)) * 8;                 // ks1: psw ^ 32
  const int aBase = (wm * 128 + l16) * 64;             // + mh*4096 + mt*1024
  const int bBase = 32768 + (wn * 64 + l16) * 64;      // + nt*1024

  f32x4 acc[8][4];
  const f32x4 zz = {0.f, 0.f, 0.f, 0.f};
#pragma unroll
  for (int i = 0; i < 8; ++i)
#pragma unroll
    for (int j2 = 0; j2 < 4; ++j2) acc[i][j2] = zz;
  s16x8 af[4], bv[4];

  // prologue: stage tile 0 fully, drain once (cold), barrier
  G_STAGE(0, 0);
  G_STAGE(0, 1);
  G_GATE(0);
  __builtin_amdgcn_s_barrier();

#pragma unroll 2
  for (int kt = 0; kt < 31; ++kt) {
    const int bufel = (kt & 1) * 16384;
    // ph0: ks0, mh0  (+ stage slot0 of kt+1 into the other buffer)
    G_LDB(bufel, 0); G_LDA(bufel, 0, 0);
    G_STAGE(kt + 1, 0);
    G_BARW(); G_MMA(0);
    __builtin_amdgcn_s_barrier();
    // ph1: ks0, mh1  (+ stage slot1 of kt+1)
    G_LDA(bufel, 0, 1);
    G_STAGE(kt + 1, 1);
    G_BARW(); G_MMA(1);
    __builtin_amdgcn_s_barrier();
    // ph2: ks1, mh0
    G_LDB(bufel, 1); G_LDA(bufel, 1, 0);
    G_BARW(); G_MMA(0);
    __builtin_amdgcn_s_barrier();
    // ph3: ks1, mh1; gate = tile kt+1 resident (stages issued 3-4 phases ago)
    G_LDA(bufel, 1, 1);
    G_BARW(); G_MMA(1);
    G_GATE(0);
    __builtin_amdgcn_s_barrier();
  }
  {  // kt = 31 (buf 1): drain tile, no staging
    G_LDB(16384, 0); G_LDA(16384, 0, 0);
    G_BARW(); G_MMA(0);
    __builtin_amdgcn_s_barrier();
    G_LDA(16384, 0, 1);
    G_BARW(); G_MMA(1);
    __builtin_amdgcn_s_barrier();
    G_LDB(16384, 1); G_LDA(16384, 1, 0);
    G_BARW(); G_MMA(0);
    __builtin_amdgcn_s_barrier();
    G_LDA(16384, 1, 1);
    G_BARW(); G_MMA(1);
  }

  // epilogue: C[m][n], row = m0 + wm*128 + mh*64 + mt*16 + q*4 + r, col += l16
#pragma unroll
  for (int mh = 0; mh < 2; ++mh)
#pragma unroll
    for (int mt = 0; mt < 4; ++mt)
#pragma unroll
      for (int nt = 0; nt < 4; ++nt)
#pragma unroll
        for (int r = 0; r < 4; ++r) {
          long m = m0 + wm * 128 + mh * 64 + mt * 16 + q * 4 + r;
          long n = n0 + wn * 64 + nt * 16 + l16;
          C[m * 2048 + n] = f2bf(acc[mh * 4 + mt][nt][r]);
        }
}

// ---------------- K_rec: persistent LSTM scan -----------------------------
__global__ __launch_bounds__(256, 1) void k_rec(const unsigned short* __restrict__ gx,
                                                const unsigned short* __restrict__ whh_b,
                                                const float* __restrict__ b_ih,
                                                const float* __restrict__ b_hh,
                                                unsigned short* __restrict__ h_buf,
                                                float* __restrict__ out,
                                                unsigned int* __restrict__ bar) {
  __shared__ unsigned short hs[32 * 528];   // h(t-1) stage, rows padded to 528
  __shared__ float gsm[4 * 32 * 36];        // [quad][colN 32][rowM pad36]
  const int tid = threadIdx.x;
  const int wave = tid >> 6, lane = tid & 63;   // wave == gate quadrant
  const int q = lane >> 4, l16 = lane & 15;
  const int bt = blockIdx.x & 15, g = blockIdx.x >> 4;
  const int b0 = bt * 32;
  const int pm = tid >> 3, pr = (tid & 7) * 4;  // pointwise: row pm, cols pr..pr+3
  const int srow = tid >> 3, st7 = tid & 7;     // stage: row srow, ull lane st7
  unsigned int* slots = &bar[bt * 16];

  // w_hh fragments -> registers (once), pinned against rematerialization
  s16x8 wreg[32];
#pragma unroll
  for (int nt = 0; nt < 2; ++nt) {
    const unsigned short* wp = whh_b + (long)(wave * 512 + g * 32 + nt * 16 + l16) * 512 + q * 8;
#pragma unroll
    for (int kk = 0; kk < 16; ++kk)
      wreg[nt * 16 + kk] = *(const s16x8*)(wp + kk * 32);
  }
#pragma unroll
  for (int i = 0; i < 32; ++i) asm volatile("" : "+v"(wreg[i]));

  float bias_[16];
#pragma unroll
  for (int qq = 0; qq < 4; ++qq)
#pragma unroll
    for (int rr = 0; rr < 4; ++rr) {
      int j = qq * 512 + g * 32 + pr + rr;
      bias_[qq * 4 + rr] = b_ih[j] + b_hh[j];
    }
  float creg[4] = {0.f, 0.f, 0.f, 0.f};
  const f32x4 zz = {0.f, 0.f, 0.f, 0.f};

  for (int t = 0; t < 48; ++t) {
    // prefetch gx (plain cached loads; read-only, L2 stays warm now)
    u16x4 gxr[4];
    const unsigned short* gp = gx + ((long)t * 512 + b0 + pm) * 2048 + g * 32 + pr;
#pragma unroll
    for (int qq = 0; qq < 4; ++qq) gxr[qq] = *(const u16x4*)(gp + qq * 512);

    f32x4 acc[2][2] = {{zz, zz}, {zz, zz}};
    if (t > 0) {
      // wait for the 16 producer slots of this bt group (relaxed sys polls)
      if (wave == 0 && lane < 16) {
        while (ld_sys_u32(&slots[lane]) < (unsigned)t)
          __builtin_amdgcn_s_sleep(1);
      }
      __syncthreads();
      // stage h(t-1)[b0:b0+32, 0:512] -> LDS (sys loads bypass stale L1/L2)
      const u64* hp = (const u64*)(h_buf + ((t - 1) & 1) * (512 * 512) + (long)b0 * 512);
      u64 tmp[16];
#pragma unroll
      for (int j = 0; j < 16; ++j)
        tmp[j] = ld_sys_u64(hp + (long)srow * 128 + st7 + 8 * j);
#pragma unroll
      for (int j = 0; j < 16; ++j)
        *(u64*)&hs[srow * 528 + (st7 + 8 * j) * 4] = tmp[j];
      __syncthreads();
#pragma unroll
      for (int kk = 0; kk < 16; ++kk) {
        s16x8 af0 = *(const s16x8*)&hs[l16 * 528 + kk * 32 + q * 8];
        s16x8 af1 = *(const s16x8*)&hs[(16 + l16) * 528 + kk * 32 + q * 8];
        acc[0][0] = __builtin_amdgcn_mfma_f32_16x16x32_bf16(af0, wreg[kk],      acc[0][0], 0, 0, 0);
        acc[0][1] = __builtin_amdgcn_mfma_f32_16x16x32_bf16(af0, wreg[16 + kk], acc[0][1], 0, 0, 0);
        acc[1][0] = __builtin_amdgcn_mfma_f32_16x16x32_bf16(af1, wreg[kk],      acc[1][0], 0, 0, 0);
        acc[1][1] = __builtin_amdgcn_mfma_f32_16x16x32_bf16(af1, wreg[16 + kk], acc[1][1], 0, 0, 0);
      }
    }
    // acc -> gsm[wave][colN][rowM]; rows mt*16+q*4..+3 contiguous => b128 store
#pragma unroll
    for (int mt = 0; mt < 2; ++mt)
#pragma unroll
      for (int nt = 0; nt < 2; ++nt)
        *(f32x4*)&gsm[(wave * 32 + nt * 16 + l16) * 36 + mt * 16 + q * 4] = acc[mt][nt];
    __syncthreads();
    // pointwise LSTM cell: thread owns (row b0+pm, cols g*32+pr..+3)
    float hval[4];
#pragma unroll
    for (int rr = 0; rr < 4; ++rr) {
      float gv[4];
#pragma unroll
      for (int qq = 0; qq < 4; ++qq)
        gv[qq] = gsm[(qq * 32 + pr + rr) * 36 + pm] + bf2f(gxr[qq][rr]) + bias_[qq * 4 + rr];
      float is = sigmoidf_(gv[0]);
      float fs = sigmoidf_(gv[1]);
      float gt = tanhf(gv[2]);
      float os = sigmoidf_(gv[3]);
      creg[rr] = fs * creg[rr] + is * gt;
      hval[rr] = os * tanhf(creg[rr]);
    }
    // publish h slice via system-scope stores (land in coherent L3)
    u16x4 hb = {f2bf(hval[0]), f2bf(hval[1]), f2bf(hval[2]), f2bf(hval[3])};
    u64 hb8;
    __builtin_memcpy(&hb8, &hb, 8);
    st_sys_u64((u64*)&h_buf[(t & 1) * (512 * 512) + (b0 + pm) * 512 + g * 32 + pr], hb8);
    f32x4 ov = {hval[0], hval[1], hval[2], hval[3]};
    __builtin_nontemporal_store(ov, (f32x4*)&out[(long)(b0 + pm) * (T_ * H_) + (long)t * H_ + g * 32 + pr]);
    __syncthreads();   // drains vmcnt(0): h stores at L3 before flag
    if (t < 47 && tid == 0)
      st_sys_u32(&slots[g], (unsigned)(t + 1));
  }
}

extern "C" void kernel_launch(void* const* d_in, const int* in_sizes, int n_in,
                              void* d_out, int out_size, void* d_ws, size_t ws_size,
                              hipStream_t stream) {
  const float* input  = (const float*)d_in[0];
  const float* attn_w = (const float*)d_in[1];
  const float* attn_b = (const float*)d_in[2];
  const float* w_ih   = (const float*)d_in[3];
  const float* w_hh   = (const float*)d_in[4];
  const float* b_ih   = (const float*)d_in[5];
  const float* b_hh   = (const float*)d_in[6];
  float* out = (float*)d_out;

  char* ws = (char*)d_ws;
  unsigned int* bar     = (unsigned int*)ws;                   // [0, 1024)
  float* a_ws           = (float*)(ws + 1024);                 // 512*128*4    = 262144
  unsigned short* h_buf = (unsigned short*)(ws + 263168);      // 2*512*512*2  = 1048576
  unsigned short* whh_b = (unsigned short*)(ws + 1311744);     // 2048*512*2   = 2097152
  unsigned short* wih_b = (unsigned short*)(ws + 3408896);     // 2048*2048*2  = 8388608
  unsigned short* x_hat = (unsigned short*)(ws + 11797504);    // 24576*2048*2 = 100663296
  unsigned short* gxws  = (unsigned short*)(ws + 112460800);   // 24576*2048*2 = 100663296

  (void)hipMemsetAsync(d_ws, 0, 1024, stream);
  hipLaunchKernelGGL(k_prep, dim3(5120), dim3(256), 0, stream, w_ih, w_hh, wih_b, whh_b);
  hipLaunchKernelGGL(k_ex, dim3(512), dim3(128), 0, stream, input, attn_w, attn_b, a_ws);
  hipLaunchKernelGGL(k_xhat, dim3(24576), dim3(256), 0, stream, input, a_ws, x_hat);
  hipLaunchKernelGGL(k_gemm, dim3(768), dim3(512), 0, stream, x_hat, wih_b, gxws);
  hipLaunchKernelGGL(k_rec, dim3(256), dim3(256), 0, stream, gxws, whh_b, b_ih, b_hh, h_buf, out, bar);
}

// Round 3
// 718.413 us; speedup vs baseline: 1.0749x; 1.0058x over previous
//
#include <hip/hip_runtime.h>

#define B_ 512
#define T_ 48
#define D_ 128
#define F_ 16
#define H_ 512
// K = D_*F_ = 2048, gates = 4*H_ = 2048, M = T_*B_ = 24576

typedef float f32x4 __attribute__((ext_vector_type(4)));
typedef short s16x8 __attribute__((ext_vector_type(8)));
typedef unsigned short u16x8 __attribute__((ext_vector_type(8)));
typedef unsigned short u16x4 __attribute__((ext_vector_type(4)));
typedef unsigned long long u64;

__device__ __forceinline__ unsigned short f2bf(float x) {
  unsigned u = __float_as_uint(x);
  u += 0x7fffu + ((u >> 16) & 1u);   // round-to-nearest-even
  return (unsigned short)(u >> 16);
}
__device__ __forceinline__ float bf2f(unsigned short h) {
  return __uint_as_float(((unsigned)h) << 16);
}
__device__ __forceinline__ float sigmoidf_(float x) {
  return 1.f / (1.f + expf(-x));
}

// Relaxed system-scope (sc0 sc1) accesses: bypass L1/L2, coherent at L3.
__device__ __forceinline__ void st_sys_u64(u64* p, u64 v) {
  __hip_atomic_store(p, v, __ATOMIC_RELAXED, __HIP_MEMORY_SCOPE_SYSTEM);
}
__device__ __forceinline__ u64 ld_sys_u64(const u64* p) {
  return __hip_atomic_load((u64*)p, __ATOMIC_RELAXED, __HIP_MEMORY_SCOPE_SYSTEM);
}
__device__ __forceinline__ void st_sys_u32(unsigned* p, unsigned v) {
  __hip_atomic_store(p, v, __ATOMIC_RELAXED, __HIP_MEMORY_SCOPE_SYSTEM);
}
__device__ __forceinline__ unsigned ld_sys_u32(const unsigned* p) {
  return __hip_atomic_load((unsigned*)p, __ATOMIC_RELAXED, __HIP_MEMORY_SCOPE_SYSTEM);
}

#define AS1 __attribute__((address_space(1)))
#define AS3 __attribute__((address_space(3)))
__device__ __forceinline__ void g2lds16(const void* g, void* l) {
  __builtin_amdgcn_global_load_lds((const AS1 void*)g, (AS3 void*)l, 16, 0, 0);
}

// ---------------- K_prep: fp32 -> bf16 weight conversion ----------------
__global__ __launch_bounds__(256) void k_prep(const float* __restrict__ wih,
                                              const float* __restrict__ whh,
                                              unsigned short* __restrict__ wih_b,
                                              unsigned short* __restrict__ whh_b) {
  long i4 = ((long)blockIdx.x * 256 + threadIdx.x) * 4;
  if (i4 < 4194304) {
    float4 v = *(const float4*)(wih + i4);
    u16x4 o = {f2bf(v.x), f2bf(v.y), f2bf(v.z), f2bf(v.w)};
    *(u16x4*)(wih_b + i4) = o;
  } else {
    long j = i4 - 4194304;
    if (j < 1048576) {
      float4 v = *(const float4*)(whh + j);
      u16x4 o = {f2bf(v.x), f2bf(v.y), f2bf(v.z), f2bf(v.w)};
      *(u16x4*)(whh_b + j) = o;
    }
  }
}

// ---------------- K_ex: e_x = x_flat @ w_x + b, then softmax over D -----
__global__ __launch_bounds__(128) void k_ex(const float* __restrict__ in,
                                            const float* __restrict__ attn_w,
                                            const float* __restrict__ attn_b,
                                            float* __restrict__ a_out) {
  __shared__ float wx[768];
  __shared__ float red[128];
  const int b = blockIdx.x, d = threadIdx.x;
  for (int i = d; i < 768; i += 128) wx[i] = attn_w[1024 + i];
  __syncthreads();
  const float* base = in + (long)b * 98304 + (long)d * 16;
  float acc = 0.f;
  for (int t = 0; t < 48; ++t) {
    const float4* p = (const float4*)(base + (long)t * 2048);
    float4 v0 = p[0], v1 = p[1], v2 = p[2], v3 = p[3];
    acc += v0.x * wx[t]       + v0.y * wx[48 + t]  + v0.z * wx[96 + t]  + v0.w * wx[144 + t];
    acc += v1.x * wx[192 + t] + v1.y * wx[240 + t] + v1.z * wx[288 + t] + v1.w * wx[336 + t];
    acc += v2.x * wx[384 + t] + v2.y * wx[432 + t] + v2.z * wx[480 + t] + v2.w * wx[528 + t];
    acc += v3.x * wx[576 + t] + v3.y * wx[624 + t] + v3.z * wx[672 + t] + v3.w * wx[720 + t];
  }
  acc += attn_b[0];
  red[d] = acc;
  __syncthreads();
  for (int s = 64; s > 0; s >>= 1) {
    if (d < s) red[d] = fmaxf(red[d], red[d + s]);
    __syncthreads();
  }
  float mx = red[0];
  __syncthreads();
  float ex = expf(acc - mx);
  red[d] = ex;
  __syncthreads();
  for (int s = 64; s > 0; s >>= 1) {
    if (d < s) red[d] += red[d + s];
    __syncthreads();
  }
  a_out[b * 128 + d] = ex / red[0];
}

// ---------------- K_xhat: x_hat[t*512+b][d*16+f] = a[b,d]*x[b,t,d,f] (bf16)
__global__ __launch_bounds__(256) void k_xhat(const float* __restrict__ in,
                                              const float* __restrict__ a,
                                              unsigned short* __restrict__ xh) {
  const int mrow = blockIdx.x;            // t*512 + b
  const int t = mrow >> 9, b = mrow & 511;
  const int tid = threadIdx.x;
  const int k = tid * 8;
  const int d = k >> 4;
  const int f0 = k & 15;
  const float* src = in + (((long)(b * 48 + t) * 128 + d) * 16 + f0);
  float4 v0 = *(const float4*)src;
  float4 v1 = *(const float4*)(src + 4);
  float s = a[b * 128 + d];
  u16x8 o;
  o[0] = f2bf(v0.x * s); o[1] = f2bf(v0.y * s); o[2] = f2bf(v0.z * s); o[3] = f2bf(v0.w * s);
  o[4] = f2bf(v1.x * s); o[5] = f2bf(v1.y * s); o[6] = f2bf(v1.z * s); o[7] = f2bf(v1.w * s);
  *(u16x8*)(xh + (long)mrow * 2048 + k) = o;
}

// ---------------- K_gemm: 256x256 pipelined bf16 MFMA GEMM ----------------
// gates_x = x_hat(24576x2048) @ w_ih^T(2048 gates x 2048 K), bf16 in/out.
// BM=BN=256, BK=64, 512 thr = 8 waves (2M x 4N); per-wave C = 128x64.
// LDS 128 KiB (1 block/CU): A [0,64K), B [64K,128K), double-buffered; row =
// full BK=64 (128 B, 8 chunks), swizzle: LDS position p holds chunk p^(r&7),
// applied at the GLOBAL source (global_load_lds writes linearly) and XORed
// on the read side -> conflict-free ds_read_b128 (verified: conflicts == 0).
// Round-2 lesson: 2 barriers + lgkmcnt(0) per phase forced CU-wide
// LDS-burst/MFMA-burst alternation (~650 idle cyc/phase -> 45% MfmaUtil).
// Now ONE barrier + ONE vmcnt(0) gate per K-tile; fragment loads are plain
// C++ ds_reads issued phase-by-phase between MFMA clusters, so the compiler
// emits counted lgkmcnt waits and the LDS port drains during MFMA.
// Lifetime check: all 4 phases of tile kt read buf kt&1; stages target
// buf^1, whose readers all passed the previous tile-end barrier. The vmcnt(0)
// gate covers the 8 stage loads issued this tile (all for kt+1).

#define G_STAGE(ktv, s)                                                         \
  do {                                                                          \
    const long ko_ = (long)(ktv) * 64 + (long)(s) * 262144;                     \
    char* la_ = (char*)SM + ((ktv) & 1) * 32768 + (s) * 16384 + ldsw;           \
    g2lds16(Ag + ko_, la_);                                                     \
    g2lds16(Ag + ko_ + 131072, la_ + 8192);                                     \
    g2lds16(Bg + ko_, la_ + 65536);                                             \
    g2lds16(Bg + ko_ + 131072, la_ + 73728);                                    \
  } while (0)

#define G_LDA4(dst, bufel, ksv, mh)                                             \
  do {                                                                          \
    const unsigned short* ab_ =                                                 \
        SM + (bufel) + aBase + (mh) * 4096 + (psw ^ ((ksv) * 32));              \
    dst[0] = *(const s16x8*)(ab_);                                              \
    dst[1] = *(const s16x8*)(ab_ + 1024);                                       \
    dst[2] = *(const s16x8*)(ab_ + 2048);                                       \
    dst[3] = *(const s16x8*)(ab_ + 3072);                                       \
  } while (0)

#define G_LDB4(dst, bufel, ksv)                                                 \
  do {                                                                          \
    const unsigned short* bb_ = SM + (bufel) + bBase + (psw ^ ((ksv) * 32));    \
    dst[0] = *(const s16x8*)(bb_);                                              \
    dst[1] = *(const s16x8*)(bb_ + 1024);                                       \
    dst[2] = *(const s16x8*)(bb_ + 2048);                                       \
    dst[3] = *(const s16x8*)(bb_ + 3072);                                       \
  } while (0)

#define G_MMA2(mh, Af, Bf)                                                      \
  do {                                                                          \
    __builtin_amdgcn_s_setprio(1);                                              \
    _Pragma("unroll") for (int mt_ = 0; mt_ < 4; ++mt_)                         \
        _Pragma("unroll") for (int nt_ = 0; nt_ < 4; ++nt_)                     \
            acc[(mh) * 4 + mt_][nt_] = __builtin_amdgcn_mfma_f32_16x16x32_bf16( \
                Af[mt_], Bf[nt_], acc[(mh) * 4 + mt_][nt_], 0, 0, 0);           \
    __builtin_amdgcn_s_setprio(0);                                              \
  } while (0)

#define G_GATE(n) asm volatile("s_waitcnt vmcnt(" #n ")" ::: "memory")

__global__ __launch_bounds__(512, 2) void k_gemm(const unsigned short* __restrict__ A,
                                                 const unsigned short* __restrict__ Bw,
                                                 unsigned short* __restrict__ C) {
  __shared__ __align__(16) unsigned short SM[65536];  // A bytes [0,64K), B [64K,128K)
  const int tid = threadIdx.x;
  const int w = tid >> 6, lane = tid & 63;
  const int q = lane >> 4, l16 = lane & 15;
  const int wm = w >> 2, wn = w & 3;
  const int id = blockIdx.x;
  const int xcd = id & 7, j = id >> 3;                 // 768 = 8 XCD * 96, bijective
  const long m0 = ((long)xcd * 12 + (j >> 3)) * 256;   // 96 m-tiles
  const long n0 = (long)(j & 7) * 256;                 // 8 n-tiles, fastest

  // staging: thread covers (row = s*128 + i*64 + w*8 + (lane>>3), pos = lane&7);
  // source chunk pre-swizzled (csrc = pos ^ (row&7)) so linear LDS lands swizzled
  const int srow = w * 8 + (lane >> 3);
  const int csrc = (lane & 7) ^ (lane >> 3);
  const unsigned short* Ag = A + (m0 + srow) * 2048 + csrc * 8;
  const unsigned short* Bg = Bw + (n0 + srow) * 2048 + csrc * 8;
  const int ldsw = w * 1024;                           // wave-uniform LDS base

  // fragment read offsets (elements); position = (ks*4+q) ^ (row&7), row&7 = l16&7
  const int psw = (q ^ (l16 & 7)) * 8;                 // ks1: psw ^ 32
  const int aBase = (wm * 128 + l16) * 64;             // + mh*4096 + mt*1024
  const int bBase = 32768 + (wn * 64 + l16) * 64;      // + nt*1024

  f32x4 acc[8][4];
  const f32x4 zz = {0.f, 0.f, 0.f, 0.f};
#pragma unroll
  for (int i = 0; i < 8; ++i)
#pragma unroll
    for (int j2 = 0; j2 < 4; ++j2) acc[i][j2] = zz;

  // prologue: stage tile 0 fully, drain once (cold), barrier
  G_STAGE(0, 0);
  G_STAGE(0, 1);
  G_GATE(0);
  __builtin_amdgcn_s_barrier();

#pragma unroll 1
  for (int kt = 0; kt < 31; ++kt) {
    const int bufel = (kt & 1) * 16384;
    s16x8 b0[4], b1[4], a00[4], a01[4], a10[4], a11[4];
    G_LDB4(b0, bufel, 0);
    G_LDA4(a00, bufel, 0, 0);
    G_STAGE(kt + 1, 0);
    G_LDA4(a01, bufel, 0, 1);
    G_STAGE(kt + 1, 1);
    G_MMA2(0, a00, b0);          // ph0; a01/b1/a10 reads drain under MFMA
    G_LDB4(b1, bufel, 1);
    G_LDA4(a10, bufel, 1, 0);
    G_MMA2(1, a01, b0);          // ph1
    G_LDA4(a11, bufel, 1, 1);
    G_MMA2(0, a10, b1);          // ph2
    G_MMA2(1, a11, b1);          // ph3
    G_GATE(0);                   // tile kt+1 staged (8 loads this tile)
    __builtin_amdgcn_s_barrier();
  }
  {  // kt = 31 (buf 1): drain tile, no staging
    s16x8 b0[4], b1[4], a00[4], a01[4], a10[4], a11[4];
    G_LDB4(b0, 16384, 0);
    G_LDA4(a00, 16384, 0, 0);
    G_LDA4(a01, 16384, 0, 1);
    G_MMA2(0, a00, b0);
    G_LDB4(b1, 16384, 1);
    G_LDA4(a10, 16384, 1, 0);
    G_MMA2(1, a01, b0);
    G_LDA4(a11, 16384, 1, 1);
    G_MMA2(0, a10, b1);
    G_MMA2(1, a11, b1);
  }

  // epilogue: C[m][n], row = m0 + wm*128 + mh*64 + mt*16 + q*4 + r, col += l16
#pragma unroll
  for (int mh = 0; mh < 2; ++mh)
#pragma unroll
    for (int mt = 0; mt < 4; ++mt)
#pragma unroll
      for (int nt = 0; nt < 4; ++nt)
#pragma unroll
        for (int r = 0; r < 4; ++r) {
          long m = m0 + wm * 128 + mh * 64 + mt * 16 + q * 4 + r;
          long n = n0 + wn * 64 + nt * 16 + l16;
          C[m * 2048 + n] = f2bf(acc[mh * 4 + mt][nt][r]);
        }
}

// ---------------- K_rec: persistent LSTM scan -----------------------------
// hs rows padded to 520 shorts (word stride 260 == 4 mod 32: conflict-free
// b128 reads, uniform u64 stage writes); gsm rows padded to 37 (stride == 5
// mod 32: kills the 4-way scalar-read conflict of pad 36). out store moved
// AFTER the barrier+flag so the flag publish no longer waits on an HBM
// store ack (off the inter-block critical path).
__global__ __launch_bounds__(256, 1) void k_rec(const unsigned short* __restrict__ gx,
                                                const unsigned short* __restrict__ whh_b,
                                                const float* __restrict__ b_ih,
                                                const float* __restrict__ b_hh,
                                                unsigned short* __restrict__ h_buf,
                                                float* __restrict__ out,
                                                unsigned int* __restrict__ bar) {
  __shared__ unsigned short hs[32 * 520];   // h(t-1) stage, rows padded to 520
  __shared__ float gsm[4 * 32 * 37];        // [quad][colN 32][rowM pad37]
  const int tid = threadIdx.x;
  const int wave = tid >> 6, lane = tid & 63;   // wave == gate quadrant
  const int q = lane >> 4, l16 = lane & 15;
  const int bt = blockIdx.x & 15, g = blockIdx.x >> 4;
  const int b0 = bt * 32;
  const int pm = tid >> 3, pr = (tid & 7) * 4;  // pointwise: row pm, cols pr..pr+3
  const int srow = tid >> 3, st7 = tid & 7;     // stage: row srow, ull lane st7
  unsigned int* slots = &bar[bt * 16];

  // w_hh fragments -> registers (once), pinned against rematerialization
  s16x8 wreg[32];
#pragma unroll
  for (int nt = 0; nt < 2; ++nt) {
    const unsigned short* wp = whh_b + (long)(wave * 512 + g * 32 + nt * 16 + l16) * 512 + q * 8;
#pragma unroll
    for (int kk = 0; kk < 16; ++kk)
      wreg[nt * 16 + kk] = *(const s16x8*)(wp + kk * 32);
  }
#pragma unroll
  for (int i = 0; i < 32; ++i) asm volatile("" : "+v"(wreg[i]));

  float bias_[16];
#pragma unroll
  for (int qq = 0; qq < 4; ++qq)
#pragma unroll
    for (int rr = 0; rr < 4; ++rr) {
      int j = qq * 512 + g * 32 + pr + rr;
      bias_[qq * 4 + rr] = b_ih[j] + b_hh[j];
    }
  float creg[4] = {0.f, 0.f, 0.f, 0.f};
  const f32x4 zz = {0.f, 0.f, 0.f, 0.f};

  for (int t = 0; t < 48; ++t) {
    // prefetch gx (plain cached loads; read-only, L2 stays warm now)
    u16x4 gxr[4];
    const unsigned short* gp = gx + ((long)t * 512 + b0 + pm) * 2048 + g * 32 + pr;
#pragma unroll
    for (int qq = 0; qq < 4; ++qq) gxr[qq] = *(const u16x4*)(gp + qq * 512);

    f32x4 acc[2][2] = {{zz, zz}, {zz, zz}};
    if (t > 0) {
      // wait for the 16 producer slots of this bt group (relaxed sys polls)
      if (wave == 0 && lane < 16) {
        while (ld_sys_u32(&slots[lane]) < (unsigned)t)
          __builtin_amdgcn_s_sleep(1);
      }
      __syncthreads();
      // stage h(t-1)[b0:b0+32, 0:512] -> LDS (sys loads bypass stale L1/L2)
      const u64* hp = (const u64*)(h_buf + ((t - 1) & 1) * (512 * 512) + (long)b0 * 512);
      u64 tmp[16];
#pragma unroll
      for (int j = 0; j < 16; ++j)
        tmp[j] = ld_sys_u64(hp + (long)srow * 128 + st7 + 8 * j);
#pragma unroll
      for (int j = 0; j < 16; ++j)
        *(u64*)&hs[srow * 520 + (st7 + 8 * j) * 4] = tmp[j];
      __syncthreads();
#pragma unroll
      for (int kk = 0; kk < 16; ++kk) {
        s16x8 af0 = *(const s16x8*)&hs[l16 * 520 + kk * 32 + q * 8];
        s16x8 af1 = *(const s16x8*)&hs[(16 + l16) * 520 + kk * 32 + q * 8];
        acc[0][0] = __builtin_amdgcn_mfma_f32_16x16x32_bf16(af0, wreg[kk],      acc[0][0], 0, 0, 0);
        acc[0][1] = __builtin_amdgcn_mfma_f32_16x16x32_bf16(af0, wreg[16 + kk], acc[0][1], 0, 0, 0);
        acc[1][0] = __builtin_amdgcn_mfma_f32_16x16x32_bf16(af1, wreg[kk],      acc[1][0], 0, 0, 0);
        acc[1][1] = __builtin_amdgcn_mfma_f32_16x16x32_bf16(af1, wreg[16 + kk], acc[1][1], 0, 0, 0);
      }
    }
    // acc -> gsm[wave][colN][rowM]; rows mt*16+q*4..+3 contiguous => b128 store
#pragma unroll
    for (int mt = 0; mt < 2; ++mt)
#pragma unroll
      for (int nt = 0; nt < 2; ++nt)
        *(f32x4*)&gsm[(wave * 32 + nt * 16 + l16) * 37 + mt * 16 + q * 4] = acc[mt][nt];
    __syncthreads();
    // pointwise LSTM cell: thread owns (row b0+pm, cols g*32+pr..+3)
    float hval[4];
#pragma unroll
    for (int rr = 0; rr < 4; ++rr) {
      float gv[4];
#pragma unroll
      for (int qq = 0; qq < 4; ++qq)
        gv[qq] = gsm[(qq * 32 + pr + rr) * 37 + pm] + bf2f(gxr[qq][rr]) + bias_[qq * 4 + rr];
      float is = sigmoidf_(gv[0]);
      float fs = sigmoidf_(gv[1]);
      float gt = tanhf(gv[2]);
      float os = sigmoidf_(gv[3]);
      creg[rr] = fs * creg[rr] + is * gt;
      hval[rr] = os * tanhf(creg[rr]);
    }
    // publish h slice via system-scope stores (land in coherent L3)
    u16x4 hb = {f2bf(hval[0]), f2bf(hval[1]), f2bf(hval[2]), f2bf(hval[3])};
    u64 hb8;
    __builtin_memcpy(&hb8, &hb, 8);
    st_sys_u64((u64*)&h_buf[(t & 1) * (512 * 512) + (b0 + pm) * 512 + g * 32 + pr], hb8);
    __syncthreads();   // drains vmcnt(0): h stores at L3 before flag
    if (t < 47 && tid == 0)
      st_sys_u32(&slots[g], (unsigned)(t + 1));
    // out store AFTER the flag publish: drains during the next step's poll
    f32x4 ov = {hval[0], hval[1], hval[2], hval[3]};
    __builtin_nontemporal_store(ov, (f32x4*)&out[(long)(b0 + pm) * (T_ * H_) + (long)t * H_ + g * 32 + pr]);
  }
}

extern "C" void kernel_launch(void* const* d_in, const int* in_sizes, int n_in,
                              void* d_out, int out_size, void* d_ws, size_t ws_size,
                              hipStream_t stream) {
  const float* input  = (const float*)d_in[0];
  const float* attn_w = (const float*)d_in[1];
  const float* attn_b = (const float*)d_in[2];
  const float* w_ih   = (const float*)d_in[3];
  const float* w_hh   = (const float*)d_in[4];
  const float* b_ih   = (const float*)d_in[5];
  const float* b_hh   = (const float*)d_in[6];
  float* out = (float*)d_out;

  char* ws = (char*)d_ws;
  unsigned int* bar     = (unsigned int*)ws;                   // [0, 1024)
  float* a_ws           = (float*)(ws + 1024);                 // 512*128*4    = 262144
  unsigned short* h_buf = (unsigned short*)(ws + 263168);      // 2*512*512*2  = 1048576
  unsigned short* whh_b = (unsigned short*)(ws + 1311744);     // 2048*512*2   = 2097152
  unsigned short* wih_b = (unsigned short*)(ws + 3408896);     // 2048*2048*2  = 8388608
  unsigned short* x_hat = (unsigned short*)(ws + 11797504);    // 24576*2048*2 = 100663296
  unsigned short* gxws  = (unsigned short*)(ws + 112460800);   // 24576*2048*2 = 100663296

  (void)hipMemsetAsync(d_ws, 0, 1024, stream);
  hipLaunchKernelGGL(k_prep, dim3(5120), dim3(256), 0, stream, w_ih, w_hh, wih_b, whh_b);
  hipLaunchKernelGGL(k_ex, dim3(512), dim3(128), 0, stream, input, attn_w, attn_b, a_ws);
  hipLaunchKernelGGL(k_xhat, dim3(24576), dim3(256), 0, stream, input, a_ws, x_hat);
  hipLaunchKernelGGL(k_gemm, dim3(768), dim3(512), 0, stream, x_hat, wih_b, gxws);
  hipLaunchKernelGGL(k_rec, dim3(256), dim3(256), 0, stream, gxws, whh_b, b_ih, b_hh, h_buf, out, bar);
}